// Round 6
// baseline (199.581 us; speedup 1.0000x reference)
//
#include <hip/hip_runtime.h>
#include <math.h>

#define DIM    256
#define NBINS  32
#define NK     33        // knots per dim
#define KSTR   65        // padded LDS stride: bank = (k + slot) % 32
#define MINSZ  1e-3f     // MIN_BIN_WIDTH == MIN_BIN_HEIGHT
#define MIND   1e-3f

// dim-within-tile -> LDS slot permutation. Thread tg owns dims 4tg..4tg+3;
// slot(4tg+j) = 16j+tg, so a fixed-knot probe hits 16 distinct banks with a
// 4-way same-address broadcast (free) instead of 8-way conflicts.
__device__ __forceinline__ int slot_of(int dl) { return ((dl & 3) << 4) | (dl >> 2); }

// Serial per-thread: softmax over 32 bins -> min-size floor -> inclusive
// cumsum -> knot table in LDS (slot sl), endpoints exactly 0 and 1.
// Two-pass exp recompute keeps live registers ~8 (params are L1/L2-hot).
__device__ __forceinline__ void build_cum(const float* __restrict__ p,
                                          float* __restrict__ s, int sl) {
    float m = p[0];
    #pragma unroll
    for (int i = 1; i < NBINS; ++i) m = fmaxf(m, p[i]);
    float ssum = 0.f;
    #pragma unroll
    for (int i = 0; i < NBINS; ++i) ssum += __expf(p[i] - m);
    const float inv = 1.f / ssum;
    const float scale = (1.f - MINSZ * NBINS) * inv;
    float c = 0.f;
    s[0 * KSTR + sl] = 0.f;
    #pragma unroll
    for (int i = 0; i < NBINS - 1; ++i) {
        c += fmaf(__expf(p[i] - m), scale, MINSZ);
        s[(i + 1) * KSTR + sl] = c;
    }
    s[(NBINS) * KSTR + sl] = 1.f;
}

// ---------------------------------------------------------------------------
// Fused kernel: each block builds its 64-dim tile's knot tables in LDS from
// the raw params (100 KB, L2-resident), then evaluates the spline over its
// row-groups. Grid = 1536 = 6 blocks/CU exactly resident (LDS 25.7 KB).
// ---------------------------------------------------------------------------
__global__ __launch_bounds__(256, 6) void spline_fused(
    const float* __restrict__ x,
    const float* __restrict__ width,    // [DIM][NBINS]
    const float* __restrict__ height,   // [DIM][NBINS]
    const float* __restrict__ deriv,    // [DIM][NBINS-1]
    float* __restrict__ yo,
    float* __restrict__ ldo,
    int nrg)                            // number of 16-row groups = rows/16
{
    __shared__ float s_cw[NK * KSTR];
    __shared__ float s_ch[NK * KSTR];
    __shared__ float s_dv[NK * KSTR];

    const int tile = blockIdx.x & 3;    // 4 dim-tiles of 64
    const int rb   = blockIdx.x >> 2;   // row-group start
    const int nrb  = gridDim.x  >> 2;   // row-group stride (384)
    const int d0   = tile * 64;

    // --- build tables: threads 0-63 widths, 64-127 heights, 128-191 derivs ---
    {
        const int tq = threadIdx.x >> 6;
        const int dl = threadIdx.x & 63;
        const int d  = d0 + dl;
        const int sl = slot_of(dl);
        if (tq == 0) {
            build_cum(width + d * NBINS, s_cw, sl);
        } else if (tq == 1) {
            build_cum(height + d * NBINS, s_ch, sl);
        } else if (tq == 2) {
            // boundary derivative == 1 exactly (MIND + softplus(log(expm1(1-MIND))))
            s_dv[0 * KSTR + sl]  = 1.f;
            s_dv[32 * KSTR + sl] = 1.f;
            #pragma unroll
            for (int i = 0; i < NBINS - 1; ++i) {
                float u  = deriv[d * (NBINS - 1) + i];
                float sp = fmaxf(u, 0.f) + log1pf(__expf(-fabsf(u)));  // stable softplus
                s_dv[(i + 1) * KSTR + sl] = MIND + sp;
            }
        }
    }
    __syncthreads();

    const int tg = threadIdx.x & 15;    // dim-subgroup within tile
    const int rg = threadIdx.x >> 4;    // row within 16-row group

    for (int g = rb; g < nrg; g += nrb) {
        const int row  = g * 16 + rg;
        const int base = row * DIM + d0 + tg * 4;
        float4 xv = *reinterpret_cast<const float4*>(x + base);
        float xs[4] = {xv.x, xv.y, xv.z, xv.w};
        float ys[4], ls[4];
        #pragma unroll
        for (int j = 0; j < 4; ++j) {
            const int sj = (j << 4) | tg;       // slot of dim d0 + 4*tg + j
            const float xo = xs[j];
            const float xc = fminf(fmaxf(xo, 0.f), 1.f);
            // binary search: largest b in [0,31] with cw[b] <= xc
            int b = 0;
            if (s_cw[16 * KSTR + sj]      <= xc) b = 16;
            if (s_cw[(b + 8) * KSTR + sj] <= xc) b += 8;
            if (s_cw[(b + 4) * KSTR + sj] <= xc) b += 4;
            if (s_cw[(b + 2) * KSTR + sj] <= xc) b += 2;
            if (s_cw[(b + 1) * KSTR + sj] <= xc) b += 1;

            const float cwb  = s_cw[b * KSTR + sj];
            const float cwb1 = s_cw[(b + 1) * KSTR + sj];
            const float chb  = s_ch[b * KSTR + sj];
            const float chb1 = s_ch[(b + 1) * KSTR + sj];
            const float db   = s_dv[b * KSTR + sj];
            const float db1  = s_dv[(b + 1) * KSTR + sj];

            const float w     = cwb1 - cwb;
            const float h     = chb1 - chb;
            const float invw  = __builtin_amdgcn_rcpf(w);
            const float delta = h * invw;
            const float theta = (xc - cwb) * invw;
            const float omt   = 1.f - theta;
            const float t1m   = theta * omt;
            const float tt    = theta * theta;

            const float num  = h * fmaf(delta, tt, db * t1m);
            const float den  = fmaf(fmaf(-2.f, delta, db + db1), t1m, delta);
            const float dinv = __builtin_amdgcn_rcpf(den);
            const float yin  = fmaf(num, dinv, chb);

            const float inner = fmaf(db1, tt, fmaf(2.f * delta, t1m, db * omt * omt));
            const float dn    = delta * delta * inner;
            const float ldin  = __logf(dn * dinv * dinv);   // log(dn) - 2log(den)

            const bool inside = (xo >= 0.f) && (xo <= 1.f);
            ys[j] = inside ? yin : xo;
            ls[j] = inside ? ldin : 0.f;
        }
        *reinterpret_cast<float4*>(yo  + base) = make_float4(ys[0], ys[1], ys[2], ys[3]);
        *reinterpret_cast<float4*>(ldo + base) = make_float4(ls[0], ls[1], ls[2], ls[3]);
    }
}

// ---------------------------------------------------------------------------
extern "C" void kernel_launch(void* const* d_in, const int* in_sizes, int n_in,
                              void* d_out, int out_size, void* d_ws, size_t ws_size,
                              hipStream_t stream) {
    const float* x      = (const float*)d_in[0];
    const float* width  = (const float*)d_in[1];
    const float* height = (const float*)d_in[2];
    const float* deriv  = (const float*)d_in[3];

    const int total = in_sizes[0];      // B * DIM
    const int rows  = total / DIM;
    const int nrg   = rows >> 4;        // 16-row groups

    float* out = (float*)d_out;
    float* yp  = out;                   // y:      [B][DIM]
    float* lp  = out + total;           // logdet: [B][DIM]

    // Single fused launch: 1536 = 6 blocks/CU x 256 CU, fully resident.
    spline_fused<<<1536, 256, 0, stream>>>(x, width, height, deriv, yp, lp, nrg);
}